// Round 16
// baseline (53.395 us; speedup 1.0000x reference)
//
#include <hip/hip_runtime.h>
#include <hip/hip_bf16.h>

#define S_LEN 2048
#define B_SZ 2
#define IN_DIM 512
#define OUT_DIM 768
#define KWIN 31
#define PAD 15
#define NGROUP 6
#define DHEAD 128
#define M_TOT 4096          // B*S
#define N_TOT 2304          // 3*OUT
#define QK_W 1536           // qk hi/lo array width (q cols 0..767, k cols 768..1535)
#define ESTR 100            // E LDS row stride (f32): 4-way -> 2-way bank spread

typedef __attribute__((ext_vector_type(8))) __bf16 bf16x8;
typedef __attribute__((ext_vector_type(8))) unsigned short u16x8;
typedef __attribute__((ext_vector_type(4))) float f32x4;

static __device__ __forceinline__ unsigned short f2bf(float f) {
  unsigned int u = __float_as_uint(f);
  unsigned int r = (u + 0x7fffu + ((u >> 16) & 1u)) >> 16;   // RNE
  return (unsigned short)r;
}
static __device__ __forceinline__ float bf2f(unsigned short h) {
  return __uint_as_float(((unsigned int)h) << 16);
}

// =====================================================================
// merged prep: bid<2048 split_x | bid<3200 split_w | bid<3293 relsplit |
// bid==3293 zero-page init (256B zeros for attn OOB lanes)
// =====================================================================
__global__ __launch_bounds__(256) void prep_kernel(
    const float* __restrict__ x,
    const float* __restrict__ Wq, const float* __restrict__ Wk, const float* __restrict__ Wv,
    const float* __restrict__ rel,
    unsigned short* __restrict__ xhi, unsigned short* __restrict__ xlo,
    unsigned short* __restrict__ whi, unsigned short* __restrict__ wlo,
    unsigned short* __restrict__ relThi, unsigned short* __restrict__ relTlo,
    unsigned short* __restrict__ zpage) {
  const int bid = blockIdx.x;
  const int tid = threadIdx.x;
  if (bid < 2048) {
    int i = bid * 256 + tid;
    float4 v = ((const float4*)x)[i];
    unsigned short h0 = f2bf(v.x), h1 = f2bf(v.y), h2 = f2bf(v.z), h3 = f2bf(v.w);
    ((ushort4*)xhi)[i] = make_ushort4(h0, h1, h2, h3);
    ((ushort4*)xlo)[i] = make_ushort4(f2bf(v.x - bf2f(h0)), f2bf(v.y - bf2f(h1)),
                                      f2bf(v.z - bf2f(h2)), f2bf(v.w - bf2f(h3)));
  } else if (bid < 3200) {
    int i = (bid - 2048) * 256 + tid;
    int e = i * 4;
    const int per = OUT_DIM * IN_DIM;
    const float* src = (e < per) ? Wq : (e < 2 * per) ? Wk : Wv;
    int rem = (e < per) ? e : (e < 2 * per) ? e - per : e - 2 * per;
    float4 v = *(const float4*)(src + rem);
    unsigned short h0 = f2bf(v.x), h1 = f2bf(v.y), h2 = f2bf(v.z), h3 = f2bf(v.w);
    ((ushort4*)whi)[i] = make_ushort4(h0, h1, h2, h3);
    ((ushort4*)wlo)[i] = make_ushort4(f2bf(v.x - bf2f(h0)), f2bf(v.y - bf2f(h1)),
                                      f2bf(v.z - bf2f(h2)), f2bf(v.w - bf2f(h3)));
  } else if (bid < 3293) {
    int idx = (bid - 3200) * 256 + tid;    // kk*768 + o, 93*256 = 23808 exact
    int kk = idx / OUT_DIM;
    int o = idx - kk * OUT_DIM;
    float v = rel[o * KWIN + kk];
    unsigned short h = f2bf(v);
    relThi[idx] = h;
    relTlo[idx] = f2bf(v - bf2f(h));
  } else {
    if (tid < 128) zpage[tid] = 0;         // 256 B zeros
  }
}

// =====================================================================
// GEMM v5 (round-9/12 best): term-fused BK=32, ONE barrier per chunk.
// BM=256 BN=128, 512 thr (8 waves, 4M x 2N, per-wave 64x64).
// 48KB slots x 3 (144KB LDS), prefetch 2 chunks ahead, counted vmcnt.
// Swizzle for 64B rows: O ^= ((O>>7)&3)<<4  (verified: 0 bank conflicts).
// qk slot: Ahi@0(16K) Alo@16384(16K) Whi@32768(8K) Wlo@40960(8K)
// v  slot: Ahi@0(16K)                Whi@32768(8K)
// =====================================================================
#define SLOTB 49152

static __device__ __forceinline__ int swz32(int O) {
  return O ^ (((O >> 7) & 3) << 4);
}

#define MFMA16(AF, BF) \
  _Pragma("unroll") for (int mi = 0; mi < 4; ++mi) \
  _Pragma("unroll") for (int ni = 0; ni < 4; ++ni) \
    acc[mi][ni] = __builtin_amdgcn_mfma_f32_16x16x32_bf16( \
        AF[mi], BF[ni], acc[mi][ni], 0, 0, 0);

#define READ_AHI() _Pragma("unroll") for (int mi = 0; mi < 4; ++mi) ahi[mi] = *(const bf16x8*)(slot + aoff[mi]);
#define READ_ALO() _Pragma("unroll") for (int mi = 0; mi < 4; ++mi) alo[mi] = *(const bf16x8*)(slot + 16384 + aoff[mi]);
#define READ_WHI() _Pragma("unroll") for (int ni = 0; ni < 4; ++ni) whi[ni] = *(const bf16x8*)(slot + 32768 + boff[ni]);
#define READ_WLO() _Pragma("unroll") for (int ni = 0; ni < 4; ++ni) wlo[ni] = *(const bf16x8*)(slot + 40960 + boff[ni]);

#define END_BARRIER() \
  __builtin_amdgcn_s_barrier(); \
  asm volatile("" ::: "memory");

__global__ __launch_bounds__(512, 2) void gemm_kernel(
    const unsigned short* __restrict__ Ahi, const unsigned short* __restrict__ Alo,
    const unsigned short* __restrict__ Whi, const unsigned short* __restrict__ Wlo,
    unsigned short* __restrict__ qkhi, unsigned short* __restrict__ qklo,
    unsigned short* __restrict__ vTw) {
  __shared__ unsigned short lds_u16[73728];   // 147456 B = 3 slots x 48KB
  char* ldsb = (char*)lds_u16;
  const int tid = threadIdx.x;
  const int wid = tid >> 6, lane = tid & 63;
  const int elr = lane & 15, elq = lane >> 4;
  const int wm = wid >> 1, wn = wid & 1;

  // frag byte offsets within regions (64B rows, swizzled)
  int aoff[4], boff[4];
#pragma unroll
  for (int mi = 0; mi < 4; ++mi)
    aoff[mi] = swz32((wm * 64 + mi * 16 + elr) * 64 + elq * 16);
#pragma unroll
  for (int ni = 0; ni < 4; ++ni)
    boff[ni] = swz32((wn * 64 + ni * 16 + elr) * 64 + elq * 16);

  // staging source coords (pre-swizzled; dest linear = tid*16 within region+8K*j)
  const int strow = tid >> 2;                                  // + j*128
  const int stcol = (((tid & 3) ^ ((tid >> 3) & 3)) << 3);     // elem col

  auto stage8k = [&](char* slot, int RO, int j, const unsigned short* src,
                     int grow0, int kloc) {
    const unsigned short* g = src + (size_t)(grow0 + j * 128 + strow) * IN_DIM + kloc + stcol;
    __builtin_amdgcn_global_load_lds((const __attribute__((address_space(1))) void*)g,
        (__attribute__((address_space(3))) void*)(slot + RO + j * 8192 + wid * 1024), 16, 0, 0);
  };

  f32x4 acc[4][4] = {};
  bf16x8 ahi[4], whi[4], alo[4], wlo[4];

  const int bid = blockIdx.x;

  if (bid < 192) {
    // ---------------- qk blocks: 3-term fused, 1 barrier/chunk ----------------
    const int bm = bid & 15, ct = bid >> 4;
    const int row0 = bm << 8, col0 = ct << 7;

    auto stageChunk = [&](int cc) {
      char* s = ldsb + (cc % 3) * SLOTB;
      const int pk = cc << 5;
      stage8k(s, 0, 0, Ahi, row0, pk);      stage8k(s, 0, 1, Ahi, row0, pk);
      stage8k(s, 16384, 0, Alo, row0, pk);  stage8k(s, 16384, 1, Alo, row0, pk);
      stage8k(s, 32768, 0, Whi, col0, pk);  stage8k(s, 40960, 0, Wlo, col0, pk);
    };

    stageChunk(0);
    stageChunk(1);
    asm volatile("s_waitcnt vmcnt(6)" ::: "memory");   // chunk 0 landed
    END_BARRIER()

    for (int c = 0; c < 16; ++c) {
      char* slot = ldsb + (c % 3) * SLOTB;
      READ_AHI()
      READ_WHI()
      READ_ALO()
      READ_WLO()
      const bool pref = (c + 2) < 16;
      if (pref) stageChunk(c + 2);          // slot (c-1)%3: all waves read it pre-barrier(c-1)
      __builtin_amdgcn_s_setprio(1);
      MFMA16(ahi, whi)
      MFMA16(alo, whi)
      MFMA16(ahi, wlo)
      __builtin_amdgcn_s_setprio(0);
      if (pref) { asm volatile("s_waitcnt vmcnt(6)" ::: "memory"); }
      else      { asm volatile("s_waitcnt vmcnt(0)" ::: "memory"); }
      END_BARRIER()
    }

    // epilogue: split f32 acc -> bf16 hi/lo [4096][1536]
    const int elg = elq * 4;
#pragma unroll
    for (int mi = 0; mi < 4; ++mi)
#pragma unroll
      for (int ni = 0; ni < 4; ++ni) {
        int ncol = col0 + wn * 64 + ni * 16 + elr;
        size_t rbase = (size_t)(row0 + wm * 64 + mi * 16 + elg);
#pragma unroll
        for (int j = 0; j < 4; ++j) {
          float v = acc[mi][ni][j];
          unsigned short h = f2bf(v);
          size_t idx = (rbase + j) * QK_W + ncol;
          qkhi[idx] = h;
          qklo[idx] = f2bf(v - bf2f(h));
        }
      }
  } else {
    // ---------------- v blocks: single term, 2 col-tiles, 1 barrier/chunk ----------------
    const int bid2 = bid - 192;                  // 0..47
    const int bm = bid2 & 15, grp = bid2 >> 4;   // grp 0..2
    const int row0 = bm << 8;
    auto vcol = [&](int ci) { return 1536 + ((grp * 2 + (ci >> 4)) << 7); };

    auto stageChunkV = [&](int cc) {
      char* s = ldsb + (cc % 3) * SLOTB;
      const int pk = (cc & 15) << 5;
      stage8k(s, 0, 0, Ahi, row0, pk);  stage8k(s, 0, 1, Ahi, row0, pk);
      stage8k(s, 32768, 0, Whi, vcol(cc), pk);
    };

    stageChunkV(0);
    stageChunkV(1);
    asm volatile("s_waitcnt vmcnt(3)" ::: "memory");
    END_BARRIER()

    for (int ci = 0; ci < 32; ++ci) {
      char* slot = ldsb + (ci % 3) * SLOTB;
      READ_AHI()
      READ_WHI()
      const bool pref = (ci + 2) < 32;
      if (pref) stageChunkV(ci + 2);
      __builtin_amdgcn_s_setprio(1);
      MFMA16(ahi, whi)
      __builtin_amdgcn_s_setprio(0);
      if (pref) { asm volatile("s_waitcnt vmcnt(3)" ::: "memory"); }
      else      { asm volatile("s_waitcnt vmcnt(0)" ::: "memory"); }
      END_BARRIER()

      if ((ci & 15) == 15) {
        // epilogue for tile: transposed bf16 vT[d][srow]
        const int col0 = vcol(ci);
        const int elg = elq * 4;
#pragma unroll
        for (int mi = 0; mi < 4; ++mi)
#pragma unroll
          for (int ni = 0; ni < 4; ++ni) {
            int d = col0 - 1536 + wn * 64 + ni * 16 + elr;
            int srw = row0 + wm * 64 + mi * 16 + elg;
            ushort4 pk4;
            pk4.x = f2bf(acc[mi][ni][0]); pk4.y = f2bf(acc[mi][ni][1]);
            pk4.z = f2bf(acc[mi][ni][2]); pk4.w = f2bf(acc[mi][ni][3]);
            *(ushort4*)(vTw + (size_t)d * M_TOT + srw) = pk4;
            acc[mi][ni] = (f32x4){0.f, 0.f, 0.f, 0.f};
          }
      }
    }
  }
}

// =====================================================================
// MFMA banded attention (round-14 verified): 3 blocks/CU (45056 B LDS).
// Klo gathered from global per cf; VT overlays dead E region AFTER
// softmax (sequential, race-free — the r15 overlap raced under replay).
// LDS: Khi[96][128] @0 (24576) | E f32[32][ESTR] / VT[128][64] @24576
//      (16384) | Ab[32][64] @40960 (4096).
// =====================================================================
__global__ __launch_bounds__(256, 3) void attn_kernel(
    const unsigned short* __restrict__ qkhi, const unsigned short* __restrict__ qklo,
    const unsigned short* __restrict__ vT,
    const unsigned short* __restrict__ relThi, const unsigned short* __restrict__ relTlo,
    const unsigned short* __restrict__ zpage,
    float* __restrict__ out, float* __restrict__ attn_out) {
  __shared__ __attribute__((aligned(16))) unsigned short smem[22528];   // 45056 B
  char* smb = (char*)smem;
  float* Elds = (float*)(smb + 24576);
  const int VT_BASE = 24576;
  const int AB_BASE = 40960;

  const int tid = threadIdx.x;
  const int wid = tid >> 6, lane = tid & 63;
  const int bid = (blockIdx.x & 7) * 96 + (blockIdx.x >> 3);   // bijective on [0,768)
  const int tile = bid & 63;
  const int g = (bid >> 6) % NGROUP;
  const int b = bid / (64 * NGROUP);
  const int s0 = tile * 32;
  const size_t rowbase = (size_t)b * S_LEN;
  const int elr = lane & 15, elq = lane >> 4;

  // ---- K hi staging via DMA
  {
    const int wrow = wid * 4 + (lane >> 4);
    const int kcb = lane & 15;
#pragma unroll
    for (int i = 0; i < 6; ++i) {
      int w = i * 16 + wrow;
      int scb = (kcb ^ (w & 7)) * 8;
      const unsigned short* gp;
      if (w < 62) {
        int r = s0 - 15 + w;
        gp = (r >= 0 && r < S_LEN)
           ? qkhi + (size_t)(rowbase + r) * QK_W + OUT_DIM + g * DHEAD + scb
           : zpage + scb;
      } else if (w < 93) {
        gp = relThi + (w - 62) * OUT_DIM + g * DHEAD + scb;
      } else {
        gp = zpage + scb;
      }
      __builtin_amdgcn_global_load_lds((const __attribute__((address_space(1))) void*)gp,
          (__attribute__((address_space(3))) void*)(smb + (i * 16 + wid * 4) * 256 + (lane & 15) * 16 + (lane >> 4) * 256),
          16, 0, 0);
    }
  }
  // ---- zero Ab
  {
    int O = tid * 16;
    O ^= (O >> 3) & 0x70;
    u16x8 z = {};
    *(u16x8*)(smb + AB_BASE + O) = z;
  }

  // ---- Q A-frags from global
  const int rf = wid & 1;
  const int cb3 = 3 * (wid >> 1);
  bf16x8 qh[4], ql[4];
  {
    size_t qrow = rowbase + s0 + rf * 16 + elr;
    const unsigned short* qb  = qkhi + qrow * QK_W + g * DHEAD + elq * 8;
    const unsigned short* qb2 = qklo + qrow * QK_W + g * DHEAD + elq * 8;
#pragma unroll
    for (int ks = 0; ks < 4; ++ks) {
      qh[ks] = *(const bf16x8*)(qb + ks * 32);
      ql[ks] = *(const bf16x8*)(qb2 + ks * 32);
    }
  }
  __syncthreads();

  // ---- E = Q·K^T: qh*kh + ql*kh + qh*kl (kl gathered from global)
#pragma unroll
  for (int cf = 0; cf < 3; ++cf) {
    int c = cb3 + cf;
    const unsigned short* klbase;
    {
      int w = c * 16 + elr;
      int r = s0 - 15 + w;
      if (w < 62)      klbase = (r >= 0 && r < S_LEN)
                                ? qklo + (size_t)(rowbase + r) * QK_W + OUT_DIM + g * DHEAD
                                : zpage;
      else if (w < 93) klbase = relTlo + (w - 62) * OUT_DIM + g * DHEAD;
      else             klbase = zpage;
    }
    bf16x8 kl[4];
#pragma unroll
    for (int ks = 0; ks < 4; ++ks)
      kl[ks] = *(const bf16x8*)(klbase + ks * 32 + elq * 8);

    f32x4 ea = {};
#pragma unroll
    for (int ks = 0; ks < 4; ++ks) {
      int O = (c * 16 + elr) * 256 + ks * 64 + elq * 16;
      int Os = O ^ ((O >> 4) & 0x70);
      bf16x8 kh = *(const bf16x8*)(smb + Os);
      __builtin_amdgcn_s_setprio(1);
      ea = __builtin_amdgcn_mfma_f32_16x16x32_bf16(qh[ks], kh, ea, 0, 0, 0);
      ea = __builtin_amdgcn_mfma_f32_16x16x32_bf16(ql[ks], kh, ea, 0, 0, 0);
      ea = __builtin_amdgcn_mfma_f32_16x16x32_bf16(qh[ks], kl[ks], ea, 0, 0, 0);
      __builtin_amdgcn_s_setprio(0);
    }
#pragma unroll
    for (int j = 0; j < 4; ++j)
      Elds[(rf * 16 + elq * 4 + j) * ESTR + c * 16 + elr] = ea[j];
  }
  __syncthreads();

  // ---- softmax
  {
    const int kkl = lane & 31;
    const int half = lane >> 5;
    const int kkc = (kkl < 31) ? kkl : 30;
#pragma unroll
    for (int p = 0; p < 4; ++p) {
      int si = p * 8 + wid * 2 + half;
      float e = Elds[si * ESTR + si + kkc] + Elds[si * ESTR + 62 + kkc];
      if (kkl == 31) e = -INFINITY;
      float m = e;
#pragma unroll
      for (int off = 16; off > 0; off >>= 1) m = fmaxf(m, __shfl_xor(m, off, 32));
      float pr = __expf(e - m);
      float sum = pr;
#pragma unroll
      for (int off = 16; off > 0; off >>= 1) sum += __shfl_xor(sum, off, 32);
      float a = pr / sum;
      if (kkl < 31) {
        attn_out[((rowbase + s0 + si) * NGROUP + g) * KWIN + kkl] = a;
        int O = si * 128 + (si + kkl + 1) * 2;
        O ^= (O >> 3) & 0x70;
        *(unsigned short*)(smb + AB_BASE + O) = f2bf(a);
      }
    }
  }
  __syncthreads();    // all E reads done -> safe to overlay VT

  // ---- VT staging via DMA into the dead E region
  {
    const unsigned short* vsrc = vT + (size_t)g * DHEAD * M_TOT + (size_t)b * S_LEN;
    const int drow = wid * 8 + (lane >> 3);
    const int vcb = lane & 7;
#pragma unroll
    for (int i = 0; i < 4; ++i) {
      int d = i * 32 + drow;
      int sl = s0 - 16 + (vcb ^ (d & 7)) * 8;
      const unsigned short* gp = (sl >= 0 && sl < S_LEN)
        ? vsrc + (size_t)d * M_TOT + sl
        : zpage + (vcb ^ (d & 7)) * 8;
      __builtin_amdgcn_global_load_lds((const __attribute__((address_space(1))) void*)gp,
          (__attribute__((address_space(3))) void*)(smb + VT_BASE + (i * 32 + wid * 8) * 128 + (lane >> 3) * 128 + (lane & 7) * 16),
          16, 0, 0);
    }
  }
  __syncthreads();

  // ---- PV
  {
    const int pcb = 4 * (wid >> 1);
    f32x4 pa[4] = {};
#pragma unroll
    for (int ks = 0; ks < 2; ++ks) {
      int AO = (rf * 16 + elr) * 128 + ks * 64 + elq * 16;
      AO ^= (AO >> 3) & 0x70;
      bf16x8 afr = *(const bf16x8*)(smb + AB_BASE + AO);
      __builtin_amdgcn_s_setprio(1);
#pragma unroll
      for (int cf = 0; cf < 4; ++cf) {
        int VO = ((pcb + cf) * 16 + elr) * 128 + ks * 64 + elq * 16;
        VO ^= (VO >> 3) & 0x70;
        bf16x8 vfr = *(const bf16x8*)(smb + VT_BASE + VO);
        pa[cf] = __builtin_amdgcn_mfma_f32_16x16x32_bf16(afr, vfr, pa[cf], 0, 0, 0);
      }
      __builtin_amdgcn_s_setprio(0);
    }
#pragma unroll
    for (int cf = 0; cf < 4; ++cf)
#pragma unroll
      for (int j = 0; j < 4; ++j)
        out[(rowbase + s0 + rf * 16 + elq * 4 + j) * OUT_DIM + g * DHEAD + pcb * 16 + cf * 16 + elr]
            = pa[cf][j];
  }
}

extern "C" void kernel_launch(void* const* d_in, const int* in_sizes, int n_in,
                              void* d_out, int out_size, void* d_ws, size_t ws_size,
                              hipStream_t stream) {
  const float* x   = (const float*)d_in[0];
  const float* Wq  = (const float*)d_in[1];
  const float* Wk  = (const float*)d_in[2];
  const float* Wv  = (const float*)d_in[3];
  const float* rel = (const float*)d_in[4];

  char* ws = (char*)d_ws;
  unsigned short* Ahi    = (unsigned short*)(ws);
  unsigned short* Alo    = (unsigned short*)(ws + 4194304);
  unsigned short* Whi    = (unsigned short*)(ws + 8388608);
  unsigned short* Wlo    = (unsigned short*)(ws + 10747904);
  unsigned short* relThi = (unsigned short*)(ws + 13107200);
  unsigned short* relTlo = (unsigned short*)(ws + 13154816);
  unsigned short* qkhi   = (unsigned short*)(ws + 13202432);
  unsigned short* qklo   = (unsigned short*)(ws + 25785344);
  unsigned short* vTw    = (unsigned short*)(ws + 38368256);
  unsigned short* zpage  = (unsigned short*)(ws + 44659712);   // 256 B zeros

  float* outp = (float*)d_out;
  float* attn = outp + (size_t)B_SZ * S_LEN * OUT_DIM;

  prep_kernel<<<3294, 256, 0, stream>>>(x, Wq, Wk, Wv, rel, Ahi, Alo, Whi, Wlo,
                                        relThi, relTlo, zpage);
  gemm_kernel<<<240, 512, 0, stream>>>(Ahi, Alo, Whi, Wlo, qkhi, qklo, vTw);
  attn_kernel<<<768, 256, 0, stream>>>(qkhi, qklo, vTw, relThi, relTlo, zpage, outp, attn);
}

// Round 17
// 53.380 us; speedup vs baseline: 1.0003x; 1.0003x over previous
//
#include <hip/hip_runtime.h>
#include <hip/hip_bf16.h>

#define S_LEN 2048
#define B_SZ 2
#define IN_DIM 512
#define OUT_DIM 768
#define KWIN 31
#define PAD 15
#define NGROUP 6
#define DHEAD 128
#define M_TOT 4096          // B*S
#define N_TOT 2304          // 3*OUT
#define QK_W 1536           // qk hi/lo array width (q cols 0..767, k cols 768..1535)
#define ESTR 100            // E LDS row stride (f32): 4-way -> 2-way bank spread

typedef __attribute__((ext_vector_type(8))) __bf16 bf16x8;
typedef __attribute__((ext_vector_type(8))) unsigned short u16x8;
typedef __attribute__((ext_vector_type(4))) float f32x4;

static __device__ __forceinline__ unsigned short f2bf(float f) {
  unsigned int u = __float_as_uint(f);
  unsigned int r = (u + 0x7fffu + ((u >> 16) & 1u)) >> 16;   // RNE
  return (unsigned short)r;
}
static __device__ __forceinline__ float bf2f(unsigned short h) {
  return __uint_as_float(((unsigned int)h) << 16);
}

// =====================================================================
// merged prep: bid<2048 split_x | bid<3200 split_w | bid<3293 relsplit |
// bid==3293 zero-page init (256B zeros for attn OOB lanes)
// =====================================================================
__global__ __launch_bounds__(256) void prep_kernel(
    const float* __restrict__ x,
    const float* __restrict__ Wq, const float* __restrict__ Wk, const float* __restrict__ Wv,
    const float* __restrict__ rel,
    unsigned short* __restrict__ xhi, unsigned short* __restrict__ xlo,
    unsigned short* __restrict__ whi, unsigned short* __restrict__ wlo,
    unsigned short* __restrict__ relThi, unsigned short* __restrict__ relTlo,
    unsigned short* __restrict__ zpage) {
  const int bid = blockIdx.x;
  const int tid = threadIdx.x;
  if (bid < 2048) {
    int i = bid * 256 + tid;
    float4 v = ((const float4*)x)[i];
    unsigned short h0 = f2bf(v.x), h1 = f2bf(v.y), h2 = f2bf(v.z), h3 = f2bf(v.w);
    ((ushort4*)xhi)[i] = make_ushort4(h0, h1, h2, h3);
    ((ushort4*)xlo)[i] = make_ushort4(f2bf(v.x - bf2f(h0)), f2bf(v.y - bf2f(h1)),
                                      f2bf(v.z - bf2f(h2)), f2bf(v.w - bf2f(h3)));
  } else if (bid < 3200) {
    int i = (bid - 2048) * 256 + tid;
    int e = i * 4;
    const int per = OUT_DIM * IN_DIM;
    const float* src = (e < per) ? Wq : (e < 2 * per) ? Wk : Wv;
    int rem = (e < per) ? e : (e < 2 * per) ? e - per : e - 2 * per;
    float4 v = *(const float4*)(src + rem);
    unsigned short h0 = f2bf(v.x), h1 = f2bf(v.y), h2 = f2bf(v.z), h3 = f2bf(v.w);
    ((ushort4*)whi)[i] = make_ushort4(h0, h1, h2, h3);
    ((ushort4*)wlo)[i] = make_ushort4(f2bf(v.x - bf2f(h0)), f2bf(v.y - bf2f(h1)),
                                      f2bf(v.z - bf2f(h2)), f2bf(v.w - bf2f(h3)));
  } else if (bid < 3293) {
    int idx = (bid - 3200) * 256 + tid;    // kk*768 + o, 93*256 = 23808 exact
    int kk = idx / OUT_DIM;
    int o = idx - kk * OUT_DIM;
    float v = rel[o * KWIN + kk];
    unsigned short h = f2bf(v);
    relThi[idx] = h;
    relTlo[idx] = f2bf(v - bf2f(h));
  } else {
    if (tid < 128) zpage[tid] = 0;         // 256 B zeros
  }
}

// =====================================================================
// GEMM v5 (round-9/12 best): term-fused BK=32, ONE barrier per chunk.
// BM=256 BN=128, 512 thr (8 waves, 4M x 2N, per-wave 64x64).
// 48KB slots x 3 (144KB LDS), prefetch 2 chunks ahead, counted vmcnt.
// Swizzle for 64B rows: O ^= ((O>>7)&3)<<4  (verified: 0 bank conflicts).
// qk slot: Ahi@0(16K) Alo@16384(16K) Whi@32768(8K) Wlo@40960(8K)
// v  slot: Ahi@0(16K)                Whi@32768(8K)
// =====================================================================
#define SLOTB 49152

static __device__ __forceinline__ int swz32(int O) {
  return O ^ (((O >> 7) & 3) << 4);
}

#define MFMA16(AF, BF) \
  _Pragma("unroll") for (int mi = 0; mi < 4; ++mi) \
  _Pragma("unroll") for (int ni = 0; ni < 4; ++ni) \
    acc[mi][ni] = __builtin_amdgcn_mfma_f32_16x16x32_bf16( \
        AF[mi], BF[ni], acc[mi][ni], 0, 0, 0);

#define READ_AHI() _Pragma("unroll") for (int mi = 0; mi < 4; ++mi) ahi[mi] = *(const bf16x8*)(slot + aoff[mi]);
#define READ_ALO() _Pragma("unroll") for (int mi = 0; mi < 4; ++mi) alo[mi] = *(const bf16x8*)(slot + 16384 + aoff[mi]);
#define READ_WHI() _Pragma("unroll") for (int ni = 0; ni < 4; ++ni) whi[ni] = *(const bf16x8*)(slot + 32768 + boff[ni]);
#define READ_WLO() _Pragma("unroll") for (int ni = 0; ni < 4; ++ni) wlo[ni] = *(const bf16x8*)(slot + 40960 + boff[ni]);

#define END_BARRIER() \
  __builtin_amdgcn_s_barrier(); \
  asm volatile("" ::: "memory");

__global__ __launch_bounds__(512, 2) void gemm_kernel(
    const unsigned short* __restrict__ Ahi, const unsigned short* __restrict__ Alo,
    const unsigned short* __restrict__ Whi, const unsigned short* __restrict__ Wlo,
    unsigned short* __restrict__ qkhi, unsigned short* __restrict__ qklo,
    unsigned short* __restrict__ vTw) {
  __shared__ unsigned short lds_u16[73728];   // 147456 B = 3 slots x 48KB
  char* ldsb = (char*)lds_u16;
  const int tid = threadIdx.x;
  const int wid = tid >> 6, lane = tid & 63;
  const int elr = lane & 15, elq = lane >> 4;
  const int wm = wid >> 1, wn = wid & 1;

  // frag byte offsets within regions (64B rows, swizzled)
  int aoff[4], boff[4];
#pragma unroll
  for (int mi = 0; mi < 4; ++mi)
    aoff[mi] = swz32((wm * 64 + mi * 16 + elr) * 64 + elq * 16);
#pragma unroll
  for (int ni = 0; ni < 4; ++ni)
    boff[ni] = swz32((wn * 64 + ni * 16 + elr) * 64 + elq * 16);

  // staging source coords (pre-swizzled; dest linear = tid*16 within region+8K*j)
  const int strow = tid >> 2;                                  // + j*128
  const int stcol = (((tid & 3) ^ ((tid >> 3) & 3)) << 3);     // elem col

  auto stage8k = [&](char* slot, int RO, int j, const unsigned short* src,
                     int grow0, int kloc) {
    const unsigned short* g = src + (size_t)(grow0 + j * 128 + strow) * IN_DIM + kloc + stcol;
    __builtin_amdgcn_global_load_lds((const __attribute__((address_space(1))) void*)g,
        (__attribute__((address_space(3))) void*)(slot + RO + j * 8192 + wid * 1024), 16, 0, 0);
  };

  f32x4 acc[4][4] = {};
  bf16x8 ahi[4], whi[4], alo[4], wlo[4];

  const int bid = blockIdx.x;

  if (bid < 192) {
    // ---------------- qk blocks: 3-term fused, 1 barrier/chunk ----------------
    const int bm = bid & 15, ct = bid >> 4;
    const int row0 = bm << 8, col0 = ct << 7;

    auto stageChunk = [&](int cc) {
      char* s = ldsb + (cc % 3) * SLOTB;
      const int pk = cc << 5;
      stage8k(s, 0, 0, Ahi, row0, pk);      stage8k(s, 0, 1, Ahi, row0, pk);
      stage8k(s, 16384, 0, Alo, row0, pk);  stage8k(s, 16384, 1, Alo, row0, pk);
      stage8k(s, 32768, 0, Whi, col0, pk);  stage8k(s, 40960, 0, Wlo, col0, pk);
    };

    stageChunk(0);
    stageChunk(1);
    asm volatile("s_waitcnt vmcnt(6)" ::: "memory");   // chunk 0 landed
    END_BARRIER()

    for (int c = 0; c < 16; ++c) {
      char* slot = ldsb + (c % 3) * SLOTB;
      READ_AHI()
      READ_WHI()
      READ_ALO()
      READ_WLO()
      const bool pref = (c + 2) < 16;
      if (pref) stageChunk(c + 2);          // slot (c-1)%3: all waves read it pre-barrier(c-1)
      __builtin_amdgcn_s_setprio(1);
      MFMA16(ahi, whi)
      MFMA16(alo, whi)
      MFMA16(ahi, wlo)
      __builtin_amdgcn_s_setprio(0);
      if (pref) { asm volatile("s_waitcnt vmcnt(6)" ::: "memory"); }
      else      { asm volatile("s_waitcnt vmcnt(0)" ::: "memory"); }
      END_BARRIER()
    }

    // epilogue: split f32 acc -> bf16 hi/lo [4096][1536]
    const int elg = elq * 4;
#pragma unroll
    for (int mi = 0; mi < 4; ++mi)
#pragma unroll
      for (int ni = 0; ni < 4; ++ni) {
        int ncol = col0 + wn * 64 + ni * 16 + elr;
        size_t rbase = (size_t)(row0 + wm * 64 + mi * 16 + elg);
#pragma unroll
        for (int j = 0; j < 4; ++j) {
          float v = acc[mi][ni][j];
          unsigned short h = f2bf(v);
          size_t idx = (rbase + j) * QK_W + ncol;
          qkhi[idx] = h;
          qklo[idx] = f2bf(v - bf2f(h));
        }
      }
  } else {
    // ---------------- v blocks: single term, 2 col-tiles, 1 barrier/chunk ----------------
    const int bid2 = bid - 192;                  // 0..47
    const int bm = bid2 & 15, grp = bid2 >> 4;   // grp 0..2
    const int row0 = bm << 8;
    auto vcol = [&](int ci) { return 1536 + ((grp * 2 + (ci >> 4)) << 7); };

    auto stageChunkV = [&](int cc) {
      char* s = ldsb + (cc % 3) * SLOTB;
      const int pk = (cc & 15) << 5;
      stage8k(s, 0, 0, Ahi, row0, pk);  stage8k(s, 0, 1, Ahi, row0, pk);
      stage8k(s, 32768, 0, Whi, vcol(cc), pk);
    };

    stageChunkV(0);
    stageChunkV(1);
    asm volatile("s_waitcnt vmcnt(3)" ::: "memory");
    END_BARRIER()

    for (int ci = 0; ci < 32; ++ci) {
      char* slot = ldsb + (ci % 3) * SLOTB;
      READ_AHI()
      READ_WHI()
      const bool pref = (ci + 2) < 32;
      if (pref) stageChunkV(ci + 2);
      __builtin_amdgcn_s_setprio(1);
      MFMA16(ahi, whi)
      __builtin_amdgcn_s_setprio(0);
      if (pref) { asm volatile("s_waitcnt vmcnt(3)" ::: "memory"); }
      else      { asm volatile("s_waitcnt vmcnt(0)" ::: "memory"); }
      END_BARRIER()

      if ((ci & 15) == 15) {
        // epilogue for tile: transposed bf16 vT[d][srow]
        const int col0 = vcol(ci);
        const int elg = elq * 4;
#pragma unroll
        for (int mi = 0; mi < 4; ++mi)
#pragma unroll
          for (int ni = 0; ni < 4; ++ni) {
            int d = col0 - 1536 + wn * 64 + ni * 16 + elr;
            int srw = row0 + wm * 64 + mi * 16 + elg;
            ushort4 pk4;
            pk4.x = f2bf(acc[mi][ni][0]); pk4.y = f2bf(acc[mi][ni][1]);
            pk4.z = f2bf(acc[mi][ni][2]); pk4.w = f2bf(acc[mi][ni][3]);
            *(ushort4*)(vTw + (size_t)d * M_TOT + srw) = pk4;
            acc[mi][ni] = (f32x4){0.f, 0.f, 0.f, 0.f};
          }
      }
    }
  }
}

// =====================================================================
// MFMA banded attention (round-14 verified): 3 blocks/CU (45056 B LDS).
// Klo gathered from global per cf; VT overlays dead E region AFTER
// softmax (sequential, race-free — the r15 overlap raced under replay).
// LDS: Khi[96][128] @0 (24576) | E f32[32][ESTR] / VT[128][64] @24576
//      (16384) | Ab[32][64] @40960 (4096).
// =====================================================================
__global__ __launch_bounds__(256, 3) void attn_kernel(
    const unsigned short* __restrict__ qkhi, const unsigned short* __restrict__ qklo,
    const unsigned short* __restrict__ vT,
    const unsigned short* __restrict__ relThi, const unsigned short* __restrict__ relTlo,
    const unsigned short* __restrict__ zpage,
    float* __restrict__ out, float* __restrict__ attn_out) {
  __shared__ __attribute__((aligned(16))) unsigned short smem[22528];   // 45056 B
  char* smb = (char*)smem;
  float* Elds = (float*)(smb + 24576);
  const int VT_BASE = 24576;
  const int AB_BASE = 40960;

  const int tid = threadIdx.x;
  const int wid = tid >> 6, lane = tid & 63;
  const int bid = (blockIdx.x & 7) * 96 + (blockIdx.x >> 3);   // bijective on [0,768)
  const int tile = bid & 63;
  const int g = (bid >> 6) % NGROUP;
  const int b = bid / (64 * NGROUP);
  const int s0 = tile * 32;
  const size_t rowbase = (size_t)b * S_LEN;
  const int elr = lane & 15, elq = lane >> 4;

  // ---- K hi staging via DMA
  {
    const int wrow = wid * 4 + (lane >> 4);
    const int kcb = lane & 15;
#pragma unroll
    for (int i = 0; i < 6; ++i) {
      int w = i * 16 + wrow;
      int scb = (kcb ^ (w & 7)) * 8;
      const unsigned short* gp;
      if (w < 62) {
        int r = s0 - 15 + w;
        gp = (r >= 0 && r < S_LEN)
           ? qkhi + (size_t)(rowbase + r) * QK_W + OUT_DIM + g * DHEAD + scb
           : zpage + scb;
      } else if (w < 93) {
        gp = relThi + (w - 62) * OUT_DIM + g * DHEAD + scb;
      } else {
        gp = zpage + scb;
      }
      __builtin_amdgcn_global_load_lds((const __attribute__((address_space(1))) void*)gp,
          (__attribute__((address_space(3))) void*)(smb + (i * 16 + wid * 4) * 256 + (lane & 15) * 16 + (lane >> 4) * 256),
          16, 0, 0);
    }
  }
  // ---- zero Ab
  {
    int O = tid * 16;
    O ^= (O >> 3) & 0x70;
    u16x8 z = {};
    *(u16x8*)(smb + AB_BASE + O) = z;
  }

  // ---- Q A-frags from global
  const int rf = wid & 1;
  const int cb3 = 3 * (wid >> 1);
  bf16x8 qh[4], ql[4];
  {
    size_t qrow = rowbase + s0 + rf * 16 + elr;
    const unsigned short* qb  = qkhi + qrow * QK_W + g * DHEAD + elq * 8;
    const unsigned short* qb2 = qklo + qrow * QK_W + g * DHEAD + elq * 8;
#pragma unroll
    for (int ks = 0; ks < 4; ++ks) {
      qh[ks] = *(const bf16x8*)(qb + ks * 32);
      ql[ks] = *(const bf16x8*)(qb2 + ks * 32);
    }
  }
  __syncthreads();

  // ---- E = Q·K^T: qh*kh + ql*kh + qh*kl (kl gathered from global)
#pragma unroll
  for (int cf = 0; cf < 3; ++cf) {
    int c = cb3 + cf;
    const unsigned short* klbase;
    {
      int w = c * 16 + elr;
      int r = s0 - 15 + w;
      if (w < 62)      klbase = (r >= 0 && r < S_LEN)
                                ? qklo + (size_t)(rowbase + r) * QK_W + OUT_DIM + g * DHEAD
                                : zpage;
      else if (w < 93) klbase = relTlo + (w - 62) * OUT_DIM + g * DHEAD;
      else             klbase = zpage;
    }
    bf16x8 kl[4];
#pragma unroll
    for (int ks = 0; ks < 4; ++ks)
      kl[ks] = *(const bf16x8*)(klbase + ks * 32 + elq * 8);

    f32x4 ea = {};
#pragma unroll
    for (int ks = 0; ks < 4; ++ks) {
      int O = (c * 16 + elr) * 256 + ks * 64 + elq * 16;
      int Os = O ^ ((O >> 4) & 0x70);
      bf16x8 kh = *(const bf16x8*)(smb + Os);
      __builtin_amdgcn_s_setprio(1);
      ea = __builtin_amdgcn_mfma_f32_16x16x32_bf16(qh[ks], kh, ea, 0, 0, 0);
      ea = __builtin_amdgcn_mfma_f32_16x16x32_bf16(ql[ks], kh, ea, 0, 0, 0);
      ea = __builtin_amdgcn_mfma_f32_16x16x32_bf16(qh[ks], kl[ks], ea, 0, 0, 0);
      __builtin_amdgcn_s_setprio(0);
    }
#pragma unroll
    for (int j = 0; j < 4; ++j)
      Elds[(rf * 16 + elq * 4 + j) * ESTR + c * 16 + elr] = ea[j];
  }
  __syncthreads();

  // ---- softmax
  {
    const int kkl = lane & 31;
    const int half = lane >> 5;
    const int kkc = (kkl < 31) ? kkl : 30;
#pragma unroll
    for (int p = 0; p < 4; ++p) {
      int si = p * 8 + wid * 2 + half;
      float e = Elds[si * ESTR + si + kkc] + Elds[si * ESTR + 62 + kkc];
      if (kkl == 31) e = -INFINITY;
      float m = e;
#pragma unroll
      for (int off = 16; off > 0; off >>= 1) m = fmaxf(m, __shfl_xor(m, off, 32));
      float pr = __expf(e - m);
      float sum = pr;
#pragma unroll
      for (int off = 16; off > 0; off >>= 1) sum += __shfl_xor(sum, off, 32);
      float a = pr / sum;
      if (kkl < 31) {
        attn_out[((rowbase + s0 + si) * NGROUP + g) * KWIN + kkl] = a;
        int O = si * 128 + (si + kkl + 1) * 2;
        O ^= (O >> 3) & 0x70;
        *(unsigned short*)(smb + AB_BASE + O) = f2bf(a);
      }
    }
  }
  __syncthreads();    // all E reads done -> safe to overlay VT

  // ---- VT staging via DMA into the dead E region
  {
    const unsigned short* vsrc = vT + (size_t)g * DHEAD * M_TOT + (size_t)b * S_LEN;
    const int drow = wid * 8 + (lane >> 3);
    const int vcb = lane & 7;
#pragma unroll
    for (int i = 0; i < 4; ++i) {
      int d = i * 32 + drow;
      int sl = s0 - 16 + (vcb ^ (d & 7)) * 8;
      const unsigned short* gp = (sl >= 0 && sl < S_LEN)
        ? vsrc + (size_t)d * M_TOT + sl
        : zpage + (vcb ^ (d & 7)) * 8;
      __builtin_amdgcn_global_load_lds((const __attribute__((address_space(1))) void*)gp,
          (__attribute__((address_space(3))) void*)(smb + VT_BASE + (i * 32 + wid * 8) * 128 + (lane >> 3) * 128 + (lane & 7) * 16),
          16, 0, 0);
    }
  }
  __syncthreads();

  // ---- PV
  {
    const int pcb = 4 * (wid >> 1);
    f32x4 pa[4] = {};
#pragma unroll
    for (int ks = 0; ks < 2; ++ks) {
      int AO = (rf * 16 + elr) * 128 + ks * 64 + elq * 16;
      AO ^= (AO >> 3) & 0x70;
      bf16x8 afr = *(const bf16x8*)(smb + AB_BASE + AO);
      __builtin_amdgcn_s_setprio(1);
#pragma unroll
      for (int cf = 0; cf < 4; ++cf) {
        int VO = ((pcb + cf) * 16 + elr) * 128 + ks * 64 + elq * 16;
        VO ^= (VO >> 3) & 0x70;
        bf16x8 vfr = *(const bf16x8*)(smb + VT_BASE + VO);
        pa[cf] = __builtin_amdgcn_mfma_f32_16x16x32_bf16(afr, vfr, pa[cf], 0, 0, 0);
      }
      __builtin_amdgcn_s_setprio(0);
    }
#pragma unroll
    for (int cf = 0; cf < 4; ++cf)
#pragma unroll
      for (int j = 0; j < 4; ++j)
        out[(rowbase + s0 + rf * 16 + elq * 4 + j) * OUT_DIM + g * DHEAD + pcb * 16 + cf * 16 + elr]
            = pa[cf][j];
  }
}

extern "C" void kernel_launch(void* const* d_in, const int* in_sizes, int n_in,
                              void* d_out, int out_size, void* d_ws, size_t ws_size,
                              hipStream_t stream) {
  const float* x   = (const float*)d_in[0];
  const float* Wq  = (const float*)d_in[1];
  const float* Wk  = (const float*)d_in[2];
  const float* Wv  = (const float*)d_in[3];
  const float* rel = (const float*)d_in[4];

  char* ws = (char*)d_ws;
  unsigned short* Ahi    = (unsigned short*)(ws);
  unsigned short* Alo    = (unsigned short*)(ws + 4194304);
  unsigned short* Whi    = (unsigned short*)(ws + 8388608);
  unsigned short* Wlo    = (unsigned short*)(ws + 10747904);
  unsigned short* relThi = (unsigned short*)(ws + 13107200);
  unsigned short* relTlo = (unsigned short*)(ws + 13154816);
  unsigned short* qkhi   = (unsigned short*)(ws + 13202432);
  unsigned short* qklo   = (unsigned short*)(ws + 25785344);
  unsigned short* vTw    = (unsigned short*)(ws + 38368256);
  unsigned short* zpage  = (unsigned short*)(ws + 44659712);   // 256 B zeros

  float* outp = (float*)d_out;
  float* attn = outp + (size_t)B_SZ * S_LEN * OUT_DIM;

  prep_kernel<<<3294, 256, 0, stream>>>(x, Wq, Wk, Wv, rel, Ahi, Alo, Whi, Wlo,
                                        relThi, relTlo, zpage);
  gemm_kernel<<<240, 512, 0, stream>>>(Ahi, Alo, Whi, Wlo, qkhi, qklo, vTw);
  attn_kernel<<<768, 256, 0, stream>>>(qkhi, qklo, vTw, relThi, relTlo, zpage, outp, attn);
}

// Round 18
// 51.194 us; speedup vs baseline: 1.0430x; 1.0427x over previous
//
#include <hip/hip_runtime.h>
#include <hip/hip_bf16.h>

#define S_LEN 2048
#define B_SZ 2
#define IN_DIM 512
#define OUT_DIM 768
#define KWIN 31
#define PAD 15
#define NGROUP 6
#define DHEAD 128
#define M_TOT 4096          // B*S
#define N_TOT 2304          // 3*OUT
#define QK_W 1536           // qk hi/lo array width (q cols 0..767, k cols 768..1535)
#define ESTR 100            // E LDS row stride (f32): 4-way -> 2-way bank spread

typedef __attribute__((ext_vector_type(8))) __bf16 bf16x8;
typedef __attribute__((ext_vector_type(8))) unsigned short u16x8;
typedef __attribute__((ext_vector_type(4))) float f32x4;

static __device__ __forceinline__ unsigned short f2bf(float f) {
  unsigned int u = __float_as_uint(f);
  unsigned int r = (u + 0x7fffu + ((u >> 16) & 1u)) >> 16;   // RNE
  return (unsigned short)r;
}
static __device__ __forceinline__ float bf2f(unsigned short h) {
  return __uint_as_float(((unsigned int)h) << 16);
}

// =====================================================================
// merged prep: bid<2048 split_x | bid<3200 split_w | bid<3293 relsplit |
// bid==3293 zero-page init (256B zeros for attn OOB lanes)
// =====================================================================
__global__ __launch_bounds__(256) void prep_kernel(
    const float* __restrict__ x,
    const float* __restrict__ Wq, const float* __restrict__ Wk, const float* __restrict__ Wv,
    const float* __restrict__ rel,
    unsigned short* __restrict__ xhi, unsigned short* __restrict__ xlo,
    unsigned short* __restrict__ whi, unsigned short* __restrict__ wlo,
    unsigned short* __restrict__ relThi, unsigned short* __restrict__ relTlo,
    unsigned short* __restrict__ zpage) {
  const int bid = blockIdx.x;
  const int tid = threadIdx.x;
  if (bid < 2048) {
    int i = bid * 256 + tid;
    float4 v = ((const float4*)x)[i];
    unsigned short h0 = f2bf(v.x), h1 = f2bf(v.y), h2 = f2bf(v.z), h3 = f2bf(v.w);
    ((ushort4*)xhi)[i] = make_ushort4(h0, h1, h2, h3);
    ((ushort4*)xlo)[i] = make_ushort4(f2bf(v.x - bf2f(h0)), f2bf(v.y - bf2f(h1)),
                                      f2bf(v.z - bf2f(h2)), f2bf(v.w - bf2f(h3)));
  } else if (bid < 3200) {
    int i = (bid - 2048) * 256 + tid;
    int e = i * 4;
    const int per = OUT_DIM * IN_DIM;
    const float* src = (e < per) ? Wq : (e < 2 * per) ? Wk : Wv;
    int rem = (e < per) ? e : (e < 2 * per) ? e - per : e - 2 * per;
    float4 v = *(const float4*)(src + rem);
    unsigned short h0 = f2bf(v.x), h1 = f2bf(v.y), h2 = f2bf(v.z), h3 = f2bf(v.w);
    ((ushort4*)whi)[i] = make_ushort4(h0, h1, h2, h3);
    ((ushort4*)wlo)[i] = make_ushort4(f2bf(v.x - bf2f(h0)), f2bf(v.y - bf2f(h1)),
                                      f2bf(v.z - bf2f(h2)), f2bf(v.w - bf2f(h3)));
  } else if (bid < 3293) {
    int idx = (bid - 3200) * 256 + tid;    // kk*768 + o, 93*256 = 23808 exact
    int kk = idx / OUT_DIM;
    int o = idx - kk * OUT_DIM;
    float v = rel[o * KWIN + kk];
    unsigned short h = f2bf(v);
    relThi[idx] = h;
    relTlo[idx] = f2bf(v - bf2f(h));
  } else {
    if (tid < 128) zpage[tid] = 0;         // 256 B zeros
  }
}

// =====================================================================
// GEMM v5m: qk path identical to round-14 best. v path merged: both
// col-tiles per chunk (16 chunks, 32 MFMA/chunk, Ahi staged ONCE),
// barriers 32->16, counted vmcnt(4). Same 3-slot/depth-2 invariant.
// qk slot: Ahi@0(16K) Alo@16384(16K) Whi@32768(8K) Wlo@40960(8K)
// v  slot: Ahi@0(16K)                W(c0)@32768(8K) W(c1)@40960(8K)
// =====================================================================
#define SLOTB 49152

static __device__ __forceinline__ int swz32(int O) {
  return O ^ (((O >> 7) & 3) << 4);
}

#define MFMA16(AF, BF) \
  _Pragma("unroll") for (int mi = 0; mi < 4; ++mi) \
  _Pragma("unroll") for (int ni = 0; ni < 4; ++ni) \
    acc[mi][ni] = __builtin_amdgcn_mfma_f32_16x16x32_bf16( \
        AF[mi], BF[ni], acc[mi][ni], 0, 0, 0);

#define MFMA16B(AF, BF) \
  _Pragma("unroll") for (int mi = 0; mi < 4; ++mi) \
  _Pragma("unroll") for (int ni = 0; ni < 4; ++ni) \
    acc2[mi][ni] = __builtin_amdgcn_mfma_f32_16x16x32_bf16( \
        AF[mi], BF[ni], acc2[mi][ni], 0, 0, 0);

#define READ_AHI() _Pragma("unroll") for (int mi = 0; mi < 4; ++mi) ahi[mi] = *(const bf16x8*)(slot + aoff[mi]);
#define READ_ALO() _Pragma("unroll") for (int mi = 0; mi < 4; ++mi) alo[mi] = *(const bf16x8*)(slot + 16384 + aoff[mi]);
#define READ_WHI() _Pragma("unroll") for (int ni = 0; ni < 4; ++ni) whi[ni] = *(const bf16x8*)(slot + 32768 + boff[ni]);
#define READ_WLO() _Pragma("unroll") for (int ni = 0; ni < 4; ++ni) wlo[ni] = *(const bf16x8*)(slot + 40960 + boff[ni]);

#define END_BARRIER() \
  __builtin_amdgcn_s_barrier(); \
  asm volatile("" ::: "memory");

__global__ __launch_bounds__(512, 2) void gemm_kernel(
    const unsigned short* __restrict__ Ahi, const unsigned short* __restrict__ Alo,
    const unsigned short* __restrict__ Whi, const unsigned short* __restrict__ Wlo,
    unsigned short* __restrict__ qkhi, unsigned short* __restrict__ qklo,
    unsigned short* __restrict__ vTw) {
  __shared__ unsigned short lds_u16[73728];   // 147456 B = 3 slots x 48KB
  char* ldsb = (char*)lds_u16;
  const int tid = threadIdx.x;
  const int wid = tid >> 6, lane = tid & 63;
  const int elr = lane & 15, elq = lane >> 4;
  const int wm = wid >> 1, wn = wid & 1;

  // frag byte offsets within regions (64B rows, swizzled)
  int aoff[4], boff[4];
#pragma unroll
  for (int mi = 0; mi < 4; ++mi)
    aoff[mi] = swz32((wm * 64 + mi * 16 + elr) * 64 + elq * 16);
#pragma unroll
  for (int ni = 0; ni < 4; ++ni)
    boff[ni] = swz32((wn * 64 + ni * 16 + elr) * 64 + elq * 16);

  // staging source coords (pre-swizzled; dest linear = tid*16 within region+8K*j)
  const int strow = tid >> 2;                                  // + j*128
  const int stcol = (((tid & 3) ^ ((tid >> 3) & 3)) << 3);     // elem col

  auto stage8k = [&](char* slot, int RO, int j, const unsigned short* src,
                     int grow0, int kloc) {
    const unsigned short* g = src + (size_t)(grow0 + j * 128 + strow) * IN_DIM + kloc + stcol;
    __builtin_amdgcn_global_load_lds((const __attribute__((address_space(1))) void*)g,
        (__attribute__((address_space(3))) void*)(slot + RO + j * 8192 + wid * 1024), 16, 0, 0);
  };

  f32x4 acc[4][4] = {};
  bf16x8 ahi[4], whi[4], alo[4], wlo[4];

  const int bid = blockIdx.x;

  if (bid < 192) {
    // ---------------- qk blocks: 3-term fused, 1 barrier/chunk (r14-identical) ----------------
    const int bm = bid & 15, ct = bid >> 4;
    const int row0 = bm << 8, col0 = ct << 7;

    auto stageChunk = [&](int cc) {
      char* s = ldsb + (cc % 3) * SLOTB;
      const int pk = cc << 5;
      stage8k(s, 0, 0, Ahi, row0, pk);      stage8k(s, 0, 1, Ahi, row0, pk);
      stage8k(s, 16384, 0, Alo, row0, pk);  stage8k(s, 16384, 1, Alo, row0, pk);
      stage8k(s, 32768, 0, Whi, col0, pk);  stage8k(s, 40960, 0, Wlo, col0, pk);
    };

    stageChunk(0);
    stageChunk(1);
    asm volatile("s_waitcnt vmcnt(6)" ::: "memory");   // chunk 0 landed
    END_BARRIER()

    for (int c = 0; c < 16; ++c) {
      char* slot = ldsb + (c % 3) * SLOTB;
      READ_AHI()
      READ_WHI()
      READ_ALO()
      READ_WLO()
      const bool pref = (c + 2) < 16;
      if (pref) stageChunk(c + 2);          // slot (c-1)%3: all waves read it pre-barrier(c-1)
      __builtin_amdgcn_s_setprio(1);
      MFMA16(ahi, whi)
      MFMA16(alo, whi)
      MFMA16(ahi, wlo)
      __builtin_amdgcn_s_setprio(0);
      if (pref) { asm volatile("s_waitcnt vmcnt(6)" ::: "memory"); }
      else      { asm volatile("s_waitcnt vmcnt(0)" ::: "memory"); }
      END_BARRIER()
    }

    // epilogue: split f32 acc -> bf16 hi/lo [4096][1536]
    const int elg = elq * 4;
#pragma unroll
    for (int mi = 0; mi < 4; ++mi)
#pragma unroll
      for (int ni = 0; ni < 4; ++ni) {
        int ncol = col0 + wn * 64 + ni * 16 + elr;
        size_t rbase = (size_t)(row0 + wm * 64 + mi * 16 + elg);
#pragma unroll
        for (int j = 0; j < 4; ++j) {
          float v = acc[mi][ni][j];
          unsigned short h = f2bf(v);
          size_t idx = (rbase + j) * QK_W + ncol;
          qkhi[idx] = h;
          qklo[idx] = f2bf(v - bf2f(h));
        }
      }
  } else {
    // ---------------- v blocks: 2 col-tiles per chunk, 16 chunks ----------------
    const int bid2 = bid - 192;                  // 0..47
    const int bm = bid2 & 15, grp = bid2 >> 4;   // grp 0..2
    const int row0 = bm << 8;
    const int col0 = 1536 + grp * 256;           // tiles at col0 and col0+128

    f32x4 acc2[4][4] = {};

    auto stageChunkV = [&](int cc) {             // 4 DMA insts
      char* s = ldsb + (cc % 3) * SLOTB;
      const int pk = cc << 5;
      stage8k(s, 0, 0, Ahi, row0, pk);  stage8k(s, 0, 1, Ahi, row0, pk);
      stage8k(s, 32768, 0, Whi, col0, pk);
      stage8k(s, 40960, 0, Whi, col0 + 128, pk);
    };

    stageChunkV(0);
    stageChunkV(1);
    asm volatile("s_waitcnt vmcnt(4)" ::: "memory");   // chunk 0 landed
    END_BARRIER()

    for (int ci = 0; ci < 16; ++ci) {
      char* slot = ldsb + (ci % 3) * SLOTB;
      READ_AHI()
      READ_WHI()                                 // col-tile 0 frags
      READ_WLO()                                 // col-tile 1 frags (region @40960)
      const bool pref = (ci + 2) < 16;
      if (pref) stageChunkV(ci + 2);
      __builtin_amdgcn_s_setprio(1);
      MFMA16(ahi, whi)
      MFMA16B(ahi, wlo)
      __builtin_amdgcn_s_setprio(0);
      if (pref) { asm volatile("s_waitcnt vmcnt(4)" ::: "memory"); }
      else      { asm volatile("s_waitcnt vmcnt(0)" ::: "memory"); }
      END_BARRIER()
    }

    // epilogue: both tiles -> transposed bf16 vT[d][srow]
    const int elg = elq * 4;
#pragma unroll
    for (int t = 0; t < 2; ++t) {
      const int colt = col0 + t * 128;
#pragma unroll
      for (int mi = 0; mi < 4; ++mi)
#pragma unroll
        for (int ni = 0; ni < 4; ++ni) {
          f32x4 a = t ? acc2[mi][ni] : acc[mi][ni];
          int d = colt - 1536 + wn * 64 + ni * 16 + elr;
          int srw = row0 + wm * 64 + mi * 16 + elg;
          ushort4 pk4;
          pk4.x = f2bf(a[0]); pk4.y = f2bf(a[1]);
          pk4.z = f2bf(a[2]); pk4.w = f2bf(a[3]);
          *(ushort4*)(vTw + (size_t)d * M_TOT + srw) = pk4;
        }
    }
  }
}

// =====================================================================
// MFMA banded attention (round-14 verified, byte-identical): 3 blocks/CU.
// LDS: Khi[96][128] @0 (24576) | E f32[32][ESTR] / VT[128][64] @24576
//      (16384) | Ab[32][64] @40960 (4096).
// =====================================================================
__global__ __launch_bounds__(256, 3) void attn_kernel(
    const unsigned short* __restrict__ qkhi, const unsigned short* __restrict__ qklo,
    const unsigned short* __restrict__ vT,
    const unsigned short* __restrict__ relThi, const unsigned short* __restrict__ relTlo,
    const unsigned short* __restrict__ zpage,
    float* __restrict__ out, float* __restrict__ attn_out) {
  __shared__ __attribute__((aligned(16))) unsigned short smem[22528];   // 45056 B
  char* smb = (char*)smem;
  float* Elds = (float*)(smb + 24576);
  const int VT_BASE = 24576;
  const int AB_BASE = 40960;

  const int tid = threadIdx.x;
  const int wid = tid >> 6, lane = tid & 63;
  const int bid = (blockIdx.x & 7) * 96 + (blockIdx.x >> 3);   // bijective on [0,768)
  const int tile = bid & 63;
  const int g = (bid >> 6) % NGROUP;
  const int b = bid / (64 * NGROUP);
  const int s0 = tile * 32;
  const size_t rowbase = (size_t)b * S_LEN;
  const int elr = lane & 15, elq = lane >> 4;

  // ---- K hi staging via DMA
  {
    const int wrow = wid * 4 + (lane >> 4);
    const int kcb = lane & 15;
#pragma unroll
    for (int i = 0; i < 6; ++i) {
      int w = i * 16 + wrow;
      int scb = (kcb ^ (w & 7)) * 8;
      const unsigned short* gp;
      if (w < 62) {
        int r = s0 - 15 + w;
        gp = (r >= 0 && r < S_LEN)
           ? qkhi + (size_t)(rowbase + r) * QK_W + OUT_DIM + g * DHEAD + scb
           : zpage + scb;
      } else if (w < 93) {
        gp = relThi + (w - 62) * OUT_DIM + g * DHEAD + scb;
      } else {
        gp = zpage + scb;
      }
      __builtin_amdgcn_global_load_lds((const __attribute__((address_space(1))) void*)gp,
          (__attribute__((address_space(3))) void*)(smb + (i * 16 + wid * 4) * 256 + (lane & 15) * 16 + (lane >> 4) * 256),
          16, 0, 0);
    }
  }
  // ---- zero Ab
  {
    int O = tid * 16;
    O ^= (O >> 3) & 0x70;
    u16x8 z = {};
    *(u16x8*)(smb + AB_BASE + O) = z;
  }

  // ---- Q A-frags from global
  const int rf = wid & 1;
  const int cb3 = 3 * (wid >> 1);
  bf16x8 qh[4], ql[4];
  {
    size_t qrow = rowbase + s0 + rf * 16 + elr;
    const unsigned short* qb  = qkhi + qrow * QK_W + g * DHEAD + elq * 8;
    const unsigned short* qb2 = qklo + qrow * QK_W + g * DHEAD + elq * 8;
#pragma unroll
    for (int ks = 0; ks < 4; ++ks) {
      qh[ks] = *(const bf16x8*)(qb + ks * 32);
      ql[ks] = *(const bf16x8*)(qb2 + ks * 32);
    }
  }
  __syncthreads();

  // ---- E = Q·K^T: qh*kh + ql*kh + qh*kl (kl gathered from global)
#pragma unroll
  for (int cf = 0; cf < 3; ++cf) {
    int c = cb3 + cf;
    const unsigned short* klbase;
    {
      int w = c * 16 + elr;
      int r = s0 - 15 + w;
      if (w < 62)      klbase = (r >= 0 && r < S_LEN)
                                ? qklo + (size_t)(rowbase + r) * QK_W + OUT_DIM + g * DHEAD
                                : zpage;
      else if (w < 93) klbase = relTlo + (w - 62) * OUT_DIM + g * DHEAD;
      else             klbase = zpage;
    }
    bf16x8 kl[4];
#pragma unroll
    for (int ks = 0; ks < 4; ++ks)
      kl[ks] = *(const bf16x8*)(klbase + ks * 32 + elq * 8);

    f32x4 ea = {};
#pragma unroll
    for (int ks = 0; ks < 4; ++ks) {
      int O = (c * 16 + elr) * 256 + ks * 64 + elq * 16;
      int Os = O ^ ((O >> 4) & 0x70);
      bf16x8 kh = *(const bf16x8*)(smb + Os);
      __builtin_amdgcn_s_setprio(1);
      ea = __builtin_amdgcn_mfma_f32_16x16x32_bf16(qh[ks], kh, ea, 0, 0, 0);
      ea = __builtin_amdgcn_mfma_f32_16x16x32_bf16(ql[ks], kh, ea, 0, 0, 0);
      ea = __builtin_amdgcn_mfma_f32_16x16x32_bf16(qh[ks], kl[ks], ea, 0, 0, 0);
      __builtin_amdgcn_s_setprio(0);
    }
#pragma unroll
    for (int j = 0; j < 4; ++j)
      Elds[(rf * 16 + elq * 4 + j) * ESTR + c * 16 + elr] = ea[j];
  }
  __syncthreads();

  // ---- softmax
  {
    const int kkl = lane & 31;
    const int half = lane >> 5;
    const int kkc = (kkl < 31) ? kkl : 30;
#pragma unroll
    for (int p = 0; p < 4; ++p) {
      int si = p * 8 + wid * 2 + half;
      float e = Elds[si * ESTR + si + kkc] + Elds[si * ESTR + 62 + kkc];
      if (kkl == 31) e = -INFINITY;
      float m = e;
#pragma unroll
      for (int off = 16; off > 0; off >>= 1) m = fmaxf(m, __shfl_xor(m, off, 32));
      float pr = __expf(e - m);
      float sum = pr;
#pragma unroll
      for (int off = 16; off > 0; off >>= 1) sum += __shfl_xor(sum, off, 32);
      float a = pr / sum;
      if (kkl < 31) {
        attn_out[((rowbase + s0 + si) * NGROUP + g) * KWIN + kkl] = a;
        int O = si * 128 + (si + kkl + 1) * 2;
        O ^= (O >> 3) & 0x70;
        *(unsigned short*)(smb + AB_BASE + O) = f2bf(a);
      }
    }
  }
  __syncthreads();    // all E reads done -> safe to overlay VT

  // ---- VT staging via DMA into the dead E region
  {
    const unsigned short* vsrc = vT + (size_t)g * DHEAD * M_TOT + (size_t)b * S_LEN;
    const int drow = wid * 8 + (lane >> 3);
    const int vcb = lane & 7;
#pragma unroll
    for (int i = 0; i < 4; ++i) {
      int d = i * 32 + drow;
      int sl = s0 - 16 + (vcb ^ (d & 7)) * 8;
      const unsigned short* gp = (sl >= 0 && sl < S_LEN)
        ? vsrc + (size_t)d * M_TOT + sl
        : zpage + (vcb ^ (d & 7)) * 8;
      __builtin_amdgcn_global_load_lds((const __attribute__((address_space(1))) void*)gp,
          (__attribute__((address_space(3))) void*)(smb + VT_BASE + (i * 32 + wid * 8) * 128 + (lane >> 3) * 128 + (lane & 7) * 16),
          16, 0, 0);
    }
  }
  __syncthreads();

  // ---- PV
  {
    const int pcb = 4 * (wid >> 1);
    f32x4 pa[4] = {};
#pragma unroll
    for (int ks = 0; ks < 2; ++ks) {
      int AO = (rf * 16 + elr) * 128 + ks * 64 + elq * 16;
      AO ^= (AO >> 3) & 0x70;
      bf16x8 afr = *(const bf16x8*)(smb + AB_BASE + AO);
      __builtin_amdgcn_s_setprio(1);
#pragma unroll
      for (int cf = 0; cf < 4; ++cf) {
        int VO = ((pcb + cf) * 16 + elr) * 128 + ks * 64 + elq * 16;
        VO ^= (VO >> 3) & 0x70;
        bf16x8 vfr = *(const bf16x8*)(smb + VT_BASE + VO);
        pa[cf] = __builtin_amdgcn_mfma_f32_16x16x32_bf16(afr, vfr, pa[cf], 0, 0, 0);
      }
      __builtin_amdgcn_s_setprio(0);
    }
#pragma unroll
    for (int cf = 0; cf < 4; ++cf)
#pragma unroll
      for (int j = 0; j < 4; ++j)
        out[(rowbase + s0 + rf * 16 + elq * 4 + j) * OUT_DIM + g * DHEAD + pcb * 16 + cf * 16 + elr]
            = pa[cf][j];
  }
}

extern "C" void kernel_launch(void* const* d_in, const int* in_sizes, int n_in,
                              void* d_out, int out_size, void* d_ws, size_t ws_size,
                              hipStream_t stream) {
  const float* x   = (const float*)d_in[0];
  const float* Wq  = (const float*)d_in[1];
  const float* Wk  = (const float*)d_in[2];
  const float* Wv  = (const float*)d_in[3];
  const float* rel = (const float*)d_in[4];

  char* ws = (char*)d_ws;
  unsigned short* Ahi    = (unsigned short*)(ws);
  unsigned short* Alo    = (unsigned short*)(ws + 4194304);
  unsigned short* Whi    = (unsigned short*)(ws + 8388608);
  unsigned short* Wlo    = (unsigned short*)(ws + 10747904);
  unsigned short* relThi = (unsigned short*)(ws + 13107200);
  unsigned short* relTlo = (unsigned short*)(ws + 13154816);
  unsigned short* qkhi   = (unsigned short*)(ws + 13202432);
  unsigned short* qklo   = (unsigned short*)(ws + 25785344);
  unsigned short* vTw    = (unsigned short*)(ws + 38368256);
  unsigned short* zpage  = (unsigned short*)(ws + 44659712);   // 256 B zeros

  float* outp = (float*)d_out;
  float* attn = outp + (size_t)B_SZ * S_LEN * OUT_DIM;

  prep_kernel<<<3294, 256, 0, stream>>>(x, Wq, Wk, Wv, rel, Ahi, Alo, Whi, Wlo,
                                        relThi, relTlo, zpage);
  gemm_kernel<<<240, 512, 0, stream>>>(Ahi, Alo, Whi, Wlo, qkhi, qklo, vTw);
  attn_kernel<<<768, 256, 0, stream>>>(qkhi, qklo, vTw, relThi, relTlo, zpage, outp, attn);
}